// Round 1
// baseline (580.981 us; speedup 1.0000x reference)
//
#include <hip/hip_runtime.h>

#define NS 128                 // samples per ray
#define NEAR_P 2.0f
#define FAR_P  6.0f

// One wave (64 lanes) per ray; each lane handles samples z0=2*lane, z1=2*lane+1.
__global__ __launch_bounds__(256) void volrender_kernel(
    const float* __restrict__ sigmas,      // [nrays, 128]
    const float* __restrict__ radiances,   // [nrays, 128, 3]
    float* __restrict__ out_rgb,           // [nrays, 3]
    float* __restrict__ out_depth,         // [nrays]
    int nrays)
{
    const int lane = threadIdx.x & 63;
    const int wave = threadIdx.x >> 6;
    const int ray  = (blockIdx.x << 2) + wave;   // 4 waves per block
    if (ray >= nrays) return;

    const float dz = (FAR_P - NEAR_P) / (float)(NS - 1);

    const float* sig = sigmas    + (size_t)ray * NS;
    const float* rad = radiances + (size_t)ray * NS * 3;

    // ---- loads ----
    const float2 s2  = *(const float2*)(sig + 2 * lane);          // sigma z0, z1
    const float2 rA  = *(const float2*)(rad + 6 * lane);          // r(z0), g(z0)
    const float2 rB  = *(const float2*)(rad + 6 * lane + 2);      // b(z0), r(z1)
    const float2 rC  = *(const float2*)(rad + 6 * lane + 4);      // g(z1), b(z1)

    const int z0 = 2 * lane;
    const int z1 = z0 + 1;
    const float d0 = dz;                                   // z0 max = 126 < 127
    const float d1 = (z1 == NS - 1) ? 1e10f : dz;

    // alpha = 1 - exp(-sigma*dist)
    const float a0 = 1.0f - __expf(-s2.x * d0);
    const float a1 = 1.0f - __expf(-s2.y * d1);

    // transmittance terms: T_step = 1 - alpha + 1e-10
    const float t0 = 1.0f - a0 + 1e-10f;
    const float t1 = 1.0f - a1 + 1e-10f;

    // local product of this lane's two steps
    float p = t0 * t1;

    // inclusive prefix product across the wave (Kogge-Stone)
    float incl = p;
    #pragma unroll
    for (int off = 1; off < 64; off <<= 1) {
        float v = __shfl_up(incl, off, 64);
        if (lane >= off) incl *= v;
    }
    // exclusive prefix (product of all preceding lanes' steps)
    float excl = __shfl_up(incl, 1, 64);
    if (lane == 0) excl = 1.0f;

    // inclusive cumprod values at z0 and z1
    const float Ts0 = excl * t0;
    const float Ts1 = Ts0 * t1;

    const float w0 = a0 * Ts0;
    const float w1 = a1 * Ts1;

    const float zv0 = NEAR_P + (float)z0 * dz;
    const float zv1 = NEAR_P + (float)z1 * dz;

    // per-lane partials
    float pr = w0 * rA.x + w1 * rB.y;
    float pg = w0 * rA.y + w1 * rC.x;
    float pb = w0 * rB.x + w1 * rC.y;
    float pd = w0 * zv0  + w1 * zv1;

    // wave tree-reduction
    #pragma unroll
    for (int off = 32; off > 0; off >>= 1) {
        pr += __shfl_down(pr, off, 64);
        pg += __shfl_down(pg, off, 64);
        pb += __shfl_down(pb, off, 64);
        pd += __shfl_down(pd, off, 64);
    }

    if (lane == 0) {
        float* o = out_rgb + (size_t)ray * 3;
        o[0] = pr;
        o[1] = pg;
        o[2] = pb;
        out_depth[ray] = pd;
    }
}

extern "C" void kernel_launch(void* const* d_in, const int* in_sizes, int n_in,
                              void* d_out, int out_size, void* d_ws, size_t ws_size,
                              hipStream_t stream) {
    const float* sigmas    = (const float*)d_in[0];
    const float* radiances = (const float*)d_in[1];
    float* out = (float*)d_out;

    const int nrays = in_sizes[0] / NS;        // B * NUM_RAYS = 262144
    float* out_rgb   = out;                    // [nrays, 3]
    float* out_depth = out + (size_t)nrays * 3;

    const int raysPerBlock = 4;                // 4 waves of 64
    const int grid = (nrays + raysPerBlock - 1) / raysPerBlock;
    volrender_kernel<<<grid, 256, 0, stream>>>(sigmas, radiances, out_rgb, out_depth, nrays);
}